// Round 3
// baseline (497.421 us; speedup 1.0000x reference)
//
#include <hip/hip_runtime.h>
#include <hip/hip_bf16.h>

typedef _Float16 half8 __attribute__((ext_vector_type(8)));
typedef float floatx4 __attribute__((ext_vector_type(4)));

// ---------------------------------------------------------------------------
// Kernel 1: Sinkhorn on the 128x128 matrix, factored form. (unchanged)
// One block, 1024 threads. Threads 0..511: (row i = t>>2, quarter q = t&3)
// own a 32-float slice of row i of A0 in regs; threads 512..1023 same for
// column i. Quarter partials combined via two __shfl_xor.
//   r = 1 / (A0 c),  c = 1 / (A0^T r),  20 iters;  P = diag(r) A0 diag(c).
// ---------------------------------------------------------------------------
__global__ __launch_bounds__(1024, 1) void sinkhorn128(
    const float* __restrict__ logits, const float* __restrict__ u,
    _Float16* __restrict__ Pout) {
    __shared__ float sA[128 * 129];           // +1 pad: conflict-free transpose
    __shared__ alignas(16) float sR[128];
    __shared__ alignas(16) float sC[128];
    const int t = threadIdx.x;

    #pragma unroll
    for (int k = 0; k < 16; ++k) {
        int e = t + (k << 10);                // e in [0,16384)
        float lg = logits[e];
        float uu = u[e];
        float g  = -logf(-logf(uu + 1e-20f) + 1e-20f);  // NOISE_SCALE = 1
        float la = (lg + g) * (1.0f / 3.0f);             // TEMPERATURE = 3
        la = fminf(10.0f, fmaxf(-10.0f, la));
        sA[(e >> 7) * 129 + (e & 127)] = expf(la);
    }
    if (t < 128) sC[t] = 1.0f;
    __syncthreads();

    const bool isRow = (t < 512);             // wave-uniform
    const int i = (t & 511) >> 2;
    const int q = t & 3;

    float a[32];                              // 32-elem slice, lives in VGPRs
    if (isRow) {
        #pragma unroll
        for (int j = 0; j < 32; ++j) a[j] = sA[i * 129 + q * 32 + j];
    } else {
        #pragma unroll
        for (int j = 0; j < 32; ++j) a[j] = sA[(q * 32 + j) * 129 + i];
    }

    float ri = 1.0f;
    for (int it = 0; it < 20; ++it) {
        if (isRow) {                          // ri = 1 / sum_j A[i][j] c[j]
            float s0 = 0.f, s1 = 0.f, s2 = 0.f, s3 = 0.f;
            #pragma unroll
            for (int j = 0; j < 32; j += 4) {
                float4 c4 = *reinterpret_cast<const float4*>(&sC[q * 32 + j]);
                s0 = fmaf(a[j + 0], c4.x, s0);
                s1 = fmaf(a[j + 1], c4.y, s1);
                s2 = fmaf(a[j + 2], c4.z, s2);
                s3 = fmaf(a[j + 3], c4.w, s3);
            }
            float p = (s0 + s1) + (s2 + s3);
            p += __shfl_xor(p, 1);
            p += __shfl_xor(p, 2);
            ri = 1.0f / p;
            if (q == 0) sR[i] = ri;
        }
        __syncthreads();
        if (!isRow) {                         // cj = 1 / sum_i A[i][j] r[i]
            float s0 = 0.f, s1 = 0.f, s2 = 0.f, s3 = 0.f;
            #pragma unroll
            for (int j = 0; j < 32; j += 4) {
                float4 r4 = *reinterpret_cast<const float4*>(&sR[q * 32 + j]);
                s0 = fmaf(a[j + 0], r4.x, s0);
                s1 = fmaf(a[j + 1], r4.y, s1);
                s2 = fmaf(a[j + 2], r4.z, s2);
                s3 = fmaf(a[j + 3], r4.w, s3);
            }
            float p = (s0 + s1) + (s2 + s3);
            p += __shfl_xor(p, 1);
            p += __shfl_xor(p, 2);
            if (q == 0) sC[i] = 1.0f / p;
        }
        __syncthreads();
    }

    if (isRow) {
        #pragma unroll
        for (int j = 0; j < 32; j += 2) {
            union { _Float16 h[2]; unsigned int w; } pk;
            pk.h[0] = (_Float16)(ri * a[j + 0] * sC[q * 32 + j + 0]);
            pk.h[1] = (_Float16)(ri * a[j + 1] * sC[q * 32 + j + 1]);
            reinterpret_cast<unsigned int*>(Pout)[(i * 128 + q * 32 + j) >> 1] = pk.w;
        }
    }
}

// ---------------------------------------------------------------------------
// Kernel 2: out = x @ P.T, streaming MFMA.
// CHANGES vs previous round (theory: latency-bound at 2 waves/SIMD because
// the 128 resident B-VGPRs + acc AGPRs filled the unified 256-reg file):
//  * B lives in LDS (32 KB), XOR-swizzled (16B chunk ^= row&7) so each
//    wave ds_read_b128 puts exactly 8 dwords on every bank (conflict floor).
//    This frees ~128 regs -> footprint ~145 -> __launch_bounds__(256,3)
//    gives 3 waves/SIMD (12 waves/CU) for latency hiding.
//  * No per-tile barriers: B is read-only after one staging __syncthreads.
//  * 1024 blocks, grid-stride: 4096 waves x 8 tiles.
// A-frag: lane holds x[row16 + (l&15)][ks*32 + (l>>4)*8 + j] (8 contig f32)
// B-frag: lane holds P[nt*16 + (l&15)][ks*32 + (l>>4)*8 + j] (8 contig f16)
// C/D:    lane l holds C[(l>>4)*4 + rr][l&15]
// ---------------------------------------------------------------------------
__global__ __launch_bounds__(256, 3) void streamMatmul(
    const float* __restrict__ x, const _Float16* __restrict__ P,
    float* __restrict__ out) {
    __shared__ _Float16 sB[128 * 128];        // 32 KB, XOR-swizzled rows
    const int tid  = threadIdx.x;
    const int lane = tid & 63;
    const int r    = lane & 15;
    const int q    = lane >> 4;
    const int s    = r & 7;

    // Stage B: 2048 16-B chunks; chunk (row, cc) stored at chunk-col cc^(row&7).
    // Write pattern puts 8 dwords on every bank per wave (floor).
    #pragma unroll
    for (int c = 0; c < 8; ++c) {
        int e   = tid + c * 256;              // chunk index 0..2047
        int row = e >> 4;
        int cc  = e & 15;
        half8 v = *reinterpret_cast<const half8*>(P + e * 8);
        *reinterpret_cast<half8*>(reinterpret_cast<char*>(sB) +
                                  row * 256 + ((cc ^ (row & 7)) << 4)) = v;
    }
    __syncthreads();                          // only barrier in the kernel

    // Per-lane swizzled column byte-offsets for the 4 k-steps.
    // B-frag chunk-col for (ks,q) is ks*4+q; row part folds to rowb + nt*4096.
    int co[4];
    #pragma unroll
    for (int ks = 0; ks < 4; ++ks) co[ks] = ((ks * 4 + q) ^ s) << 4;
    const int rowb = r * 256;
    const char* sBb = reinterpret_cast<const char*>(sB);

    const int gw = blockIdx.x * 4 + (tid >> 6);   // 0..4095
    const float* xp0 = x + (long)gw * 16 * 128 + r * 128 + q * 8;

    // Prologue: load tile 0 (tiles stride 4096*2048 floats apart)
    floatx4 xa[4][2];
    #pragma unroll
    for (int ks = 0; ks < 4; ++ks) {
        xa[ks][0] = *reinterpret_cast<const floatx4*>(xp0 + ks * 32);
        xa[ks][1] = *reinterpret_cast<const floatx4*>(xp0 + ks * 32 + 4);
    }

    for (int t = 0; t < 8; ++t) {
        // Convert current tile to f16 hi + lo (frees xa for the prefetch)
        half8 ah[4], al[4];
        #pragma unroll
        for (int ks = 0; ks < 4; ++ks)
            #pragma unroll
            for (int jj = 0; jj < 8; ++jj) {
                float f = (jj < 4) ? xa[ks][0][jj] : xa[ks][1][jj - 4];
                _Float16 h = (_Float16)f;
                ah[ks][jj] = h;
                al[ks][jj] = (_Float16)(f - (float)h);
            }

        // Prefetch next tile while MFMA + LDS reads run
        if (t < 7) {
            const float* xp = xp0 + (long)(t + 1) * 4096 * 2048;
            #pragma unroll
            for (int ks = 0; ks < 4; ++ks) {
                xa[ks][0] = *reinterpret_cast<const floatx4*>(xp + ks * 32);
                xa[ks][1] = *reinterpret_cast<const floatx4*>(xp + ks * 32 + 4);
            }
        }

        floatx4 acc[8];
        #pragma unroll
        for (int nt = 0; nt < 8; ++nt) acc[nt] = (floatx4){0.f, 0.f, 0.f, 0.f};

        #pragma unroll
        for (int ks = 0; ks < 4; ++ks) {
            half8 bf[8];
            #pragma unroll
            for (int nt = 0; nt < 8; ++nt)
                bf[nt] = *reinterpret_cast<const half8*>(
                    sBb + rowb + co[ks] + nt * 4096);
            #pragma unroll
            for (int nt = 0; nt < 8; ++nt) {
                acc[nt] = __builtin_amdgcn_mfma_f32_16x16x32_f16(
                    ah[ks], bf[nt], acc[nt], 0, 0, 0);
                acc[nt] = __builtin_amdgcn_mfma_f32_16x16x32_f16(
                    al[ks], bf[nt], acc[nt], 0, 0, 0);
            }
        }

        // Store: lane l owns rows (q*4 + rr), col (nt*16 + r); 64-B segments.
        const long m0 = (long)(gw + t * 4096) * 16;
        float* op = out + (m0 + q * 4) * 128 + r;
        #pragma unroll
        for (int nt = 0; nt < 8; ++nt)
            #pragma unroll
            for (int rr = 0; rr < 4; ++rr)
                __builtin_nontemporal_store(acc[nt][rr], op + rr * 128 + nt * 16);
    }
}

extern "C" void kernel_launch(void* const* d_in, const int* in_sizes, int n_in,
                              void* d_out, int out_size, void* d_ws, size_t ws_size,
                              hipStream_t stream) {
    (void)in_sizes; (void)n_in; (void)out_size; (void)ws_size;
    const float* x      = (const float*)d_in[0];  // [524288,128] f32
    const float* logits = (const float*)d_in[1];  // [128,128] f32
    const float* u      = (const float*)d_in[2];  // [128,128] f32
    float* out          = (float*)d_out;          // [524288,128] f32
    _Float16* P         = (_Float16*)d_ws;        // [128,128] f16 scratch

    sinkhorn128<<<1, 1024, 0, stream>>>(logits, u, P);
    streamMatmul<<<1024, 256, 0, stream>>>(x, P, out);
}